// Round 13
// baseline (241.179 us; speedup 1.0000x reference)
//
#include <hip/hip_runtime.h>
#include <hip/hip_bf16.h>
#include <stdint.h>

// GINE edge layer on MI355X:
//   de = concat([e, x[src], x[dst]]) @ W1 + b1 ; de = silu(de); h = e + de
//   out = GraphNorm(h, seg=batch[src])  (per-graph mean/var, ms-scaled mean)
// Decomposition: concat@W1 = e@W1a + xb[src] + xc[dst], xb/xc per NODE.
// GraphNorm one-pass: var = E[h^2] - m^2*ms*(2-ms); out = A[g,d]*h + C[g,d].
// R2/R3: LDS fp-atomic RMW serializes -> MFMA one-hot segsum.
// R5/R6: e re-read killed; gather chain vectorized (bf16 xbc + b1 fold).
// R7-R10: occupancy/pipelining sweeps; R10 persistent+resident-W = 99us.
// R11/R12: fused sums +54us -- 1-blk/CU persistent = every phase fully serial.
//   REVERTED to split sums.
// R13: W out of LDS entirely -- B-frags streamed from L2 (W is 128KB, L2-hot),
//   register-pipelined 1 kk ahead. LDS = 16KB e-tile only -> 5 blk/CU, 20
//   waves, 3 barriers/block, no vmcnt(0) drains in the K-loop. e-streams of
//   co-resident blocks interleave (R10's serial e-stream was the 99us wall).

typedef float   f32x4 __attribute__((ext_vector_type(4)));
typedef short   s16x8 __attribute__((ext_vector_type(8)));
typedef uint32_t u32x4 __attribute__((ext_vector_type(4)));

#define NGRAPH 64
#define SUMNB  256                      // k_sums grid; partial stride below
#define PSTRIDE (NGRAPH * 256 * 2 + NGRAPH)   // floats per block-partial: sum|sq|cnt

__device__ __forceinline__ void gld16(const void* g, void* l) {
  __builtin_amdgcn_global_load_lds(
      (const __attribute__((address_space(1))) uint32_t*)g,
      (__attribute__((address_space(3))) uint32_t*)l, 16, 0, 0);
}

// native LDS f32 add, no return (tiny per-row counts / fallback only)
__device__ __forceinline__ void ds_addf(float* p, float v) {
  asm volatile("ds_add_f32 %0, %1"
               :: "v"((__attribute__((address_space(3))) float*)p), "v"(v));
}

__device__ __forceinline__ short f2bf(float f) {
  __bf16 b = (__bf16)f;                       // RTNE
  return __builtin_bit_cast(short, b);
}
__device__ __forceinline__ float bf2f(uint32_t u) {
  return __uint_as_float((u & 0xffffu) << 16);
}

// legacy-path permuted d-index (atomic fallback kernel only)
__device__ __forceinline__ int dperm(int d) { return (d >> 3) | ((d & 7) << 5); }

// ---------------------------------------------------------------- zero tables
__global__ __launch_bounds__(256) void k_zero(float* p, int n) {
  int i = blockIdx.x * 256 + threadIdx.x;
  if (i < n) p[i] = 0.f;
}

// ------------------------------------------- W1 f32 [768][256] -> transposed bf16
__global__ __launch_bounds__(256) void k_wconv(const float* __restrict__ W1,
                                               uint16_t* __restrict__ wta,
                                               uint16_t* __restrict__ wtbc) {
  int k = blockIdx.x;            // 0..767
  int n = threadIdx.x;           // 0..255
  uint16_t v = (uint16_t)f2bf(W1[k * 256 + n]);
  if (k < 256)      wta[n * 256 + k] = v;
  else if (k < 512) wtbc[n * 256 + (k - 256)] = v;
  else              wtbc[(n + 256) * 256 + (k - 512)] = v;
}

// ------------------------------------------------- node GEMM: xbc = x @ Wbc (bf16 out)
// xbc[node][0..256) = x@W1b ; xbc[node][256..512) = x@W1c + b1  (b1 folded)
__global__ __launch_bounds__(256, 2) void k_nodegemm(const float* __restrict__ x,
                                                     const uint16_t* __restrict__ wtbc,
                                                     const float* __restrict__ b1,
                                                     uint16_t* __restrict__ xbc, int NV) {
  __shared__ float    xt[32 * 64];
  __shared__ uint16_t wtb[512 * 64];
  const int tid = threadIdx.x, wave = tid >> 6, lane = tid & 63;
  const int m0 = blockIdx.x * 32;
  const int cl = lane & 15, rq = lane >> 4;

  f32x4 acc[2][8];
#pragma unroll
  for (int a = 0; a < 2; ++a)
#pragma unroll
    for (int b = 0; b < 8; ++b) acc[a][b] = (f32x4)0.f;

  for (int kk = 0; kk < 4; ++kk) {
    const int k0 = kk * 64;
#pragma unroll
    for (int ii = 0; ii < 2; ++ii) {
      int i = wave * 2 + ii;
      int row = i * 4 + rq;
      int k8 = cl ^ (row & 15);
      int grow = m0 + row; if (grow > NV - 1) grow = NV - 1;
      gld16((const char*)x + ((size_t)grow * 256 + k0) * 4 + k8 * 16,
            (char*)xt + i * 1024);
    }
#pragma unroll
    for (int ii = 0; ii < 16; ++ii) {
      int i = wave * 16 + ii;
      int n = i * 8 + (lane >> 3);
      int k8 = (lane & 7) ^ (n & 7);
      gld16((const char*)wtbc + ((size_t)n * 256 + k0) * 2 + k8 * 16,
            (char*)wtb + i * 1024);
    }
    __syncthreads();
#pragma unroll
    for (int ks = 0; ks < 2; ++ks) {
      s16x8 a[2], b[8];
#pragma unroll
      for (int mt = 0; mt < 2; ++mt) {
        int row = mt * 16 + cl;
        int sbase = ks * 8 + rq * 2;
        int sw = (row & 15) << 4;
        f32x4 f0 = *(const f32x4*)((const char*)xt + row * 256 + (((sbase    ) << 4) ^ sw));
        f32x4 f1 = *(const f32x4*)((const char*)xt + row * 256 + (((sbase + 1) << 4) ^ sw));
        s16x8 t;
        t[0] = f2bf(f0[0]); t[1] = f2bf(f0[1]); t[2] = f2bf(f0[2]); t[3] = f2bf(f0[3]);
        t[4] = f2bf(f1[0]); t[5] = f2bf(f1[1]); t[6] = f2bf(f1[2]); t[7] = f2bf(f1[3]);
        a[mt] = t;
      }
#pragma unroll
      for (int nt = 0; nt < 8; ++nt) {
        int n = wave * 128 + nt * 16 + cl;
        int byt = n * 128 + ((((ks * 4 + rq)) << 4) ^ ((n & 7) << 4));
        b[nt] = *(const s16x8*)((const char*)wtb + byt);
      }
#pragma unroll
      for (int mt = 0; mt < 2; ++mt)
#pragma unroll
        for (int nt = 0; nt < 8; ++nt)
          acc[mt][nt] = __builtin_amdgcn_mfma_f32_16x16x32_bf16(a[mt], b[nt], acc[mt][nt], 0, 0, 0);
    }
    __syncthreads();
  }
  float b1v[8];
#pragma unroll
  for (int nt = 0; nt < 8; ++nt) {
    int col = wave * 128 + nt * 16 + cl;
    b1v[nt] = (col >= 256) ? b1[col - 256] : 0.f;
  }
#pragma unroll
  for (int mt = 0; mt < 2; ++mt)
#pragma unroll
    for (int q = 0; q < 4; ++q) {
      int row = m0 + mt * 16 + rq * 4 + q;
      if (row < NV) {
#pragma unroll
        for (int nt = 0; nt < 8; ++nt) {
          int col = wave * 128 + nt * 16 + cl;
          xbc[(size_t)row * 512 + col] = (uint16_t)f2bf(acc[mt][nt][q] + b1v[nt]);
        }
      }
    }
}

// ------------------------------------------------- edge GEMM + epilogue
// BM=32, BN=256; 256 thr, 4 waves, wave w owns cols [w*64, w*64+64).
// LDS = et[32][256] bf16 ONLY (16 KB, chunk-major:
//   byte = c8*512 + ((r*16)^((c8&3)<<4)) + (col&7)*2), 5 blocks/CU.
// B-frags stream DIRECTLY from wta in L2 (128 KB, hot), reg-pipelined 1 kk
// ahead. No W staging, no vmcnt(0) drains; 3 barriers per block total.
template <bool BF16H>
__global__ __launch_bounds__(256, 5) void k_edgegemm(
    const float* __restrict__ e, const uint16_t* __restrict__ wta,
    const uint16_t* __restrict__ xbc,
    const int* __restrict__ srcI, const int* __restrict__ dstI,
    const int* __restrict__ batch, void* __restrict__ hout,
    int* __restrict__ seg, int E) {
  __shared__ alignas(16) uint16_t et[32 * 256];   // 16 KB
  const int tid = threadIdx.x, wave = tid >> 6, lane = tid & 63;
  const int m0 = blockIdx.x * 32;
  const int cl = lane & 15, rq = lane >> 4;

  // per-thread row assignment (e-staging and epilogue share it)
  const int rr = tid >> 3;                 // 0..31
  const int cb = tid & 7;                  // chunk base
  const int rg = m0 + rr;
  const bool valid = rg < E;
  const int rgc = valid ? rg : E - 1;
  const int sA = srcI[rgc], dA = dstI[rgc];
  const int gseg = batch[sA];

  // ---- stage e rows [m0, m0+32) as bf16, once ----
  {
    const float* ep = e + (size_t)rgc * 256;
#pragma unroll
    for (int i = 0; i < 4; ++i) {
      int s = cb + 8 * i;                 // chunk 0..31 (8 bf16 each)
      f32x4 f0 = *(const f32x4*)(ep + s * 8);
      f32x4 f1 = *(const f32x4*)(ep + s * 8 + 4);
      s16x8 t;
      t[0] = f2bf(f0[0]); t[1] = f2bf(f0[1]); t[2] = f2bf(f0[2]); t[3] = f2bf(f0[3]);
      t[4] = f2bf(f1[0]); t[5] = f2bf(f1[1]); t[6] = f2bf(f1[2]); t[7] = f2bf(f1[3]);
      *(s16x8*)((char*)et + s * 512 + ((rr * 16) ^ ((s & 3) << 4))) = t;
    }
  }

  // B base for this wave/lane: n = wave*64 + nt*16 + cl (nt stride 16*256 elts),
  // k = kk*32 + rq*8 (kk stride 32 elts). wta is [n][k], k-contiguous.
  const uint16_t* wbase = wta + ((size_t)(wave * 64 + cl) * 256 + rq * 8);

  f32x4 acc[2][4];
#pragma unroll
  for (int a = 0; a < 2; ++a)
#pragma unroll
    for (int b = 0; b < 4; ++b) acc[a][b] = (f32x4)0.f;

  s16x8 bcur[4], bnext[4];
#pragma unroll
  for (int nt = 0; nt < 4; ++nt)
    bcur[nt] = *(const s16x8*)(wbase + nt * 4096);

  __syncthreads();                         // et visible

#pragma unroll
  for (int kk = 0; kk < 8; ++kk) {        // barrier-free K-loop
    if (kk < 7) {
#pragma unroll
      for (int nt = 0; nt < 4; ++nt)
        bnext[nt] = *(const s16x8*)(wbase + nt * 4096 + (kk + 1) * 32);
    }
    s16x8 a[2];
#pragma unroll
    for (int mt = 0; mt < 2; ++mt) {
      int row = mt * 16 + cl;
      int c8s = kk * 4 + rq;              // (c8s&3) == rq
      a[mt] = *(const s16x8*)((const char*)et + c8s * 512 + ((row * 16) ^ (rq << 4)));
    }
#pragma unroll
    for (int mt = 0; mt < 2; ++mt)
#pragma unroll
      for (int nt = 0; nt < 4; ++nt)
        acc[mt][nt] = __builtin_amdgcn_mfma_f32_16x16x32_bf16(a[mt], bcur[nt], acc[mt][nt], 0, 0, 0);
#pragma unroll
    for (int nt = 0; nt < 4; ++nt) bcur[nt] = bnext[nt];
  }

  // ---- xbc gathers (L2/L3; hidden under ev extract + relayout) ----
  u32x4 gb[4], gc[4];
#pragma unroll
  for (int i = 0; i < 4; ++i) {
    int c8 = cb + 8 * i;
    gb[i] = *(const u32x4*)(xbc + (size_t)sA * 512 + c8 * 8);
    gc[i] = *(const u32x4*)(xbc + (size_t)dA * 512 + 256 + c8 * 8);
  }
  // ---- e residual out of et before relayout clobbers it ----
  s16x8 ev[4];
#pragma unroll
  for (int i = 0; i < 4; ++i) {
    int c8 = cb + 8 * i;
    ev[i] = *(const s16x8*)((const char*)et + c8 * 512 + ((rr * 16) ^ ((c8 & 3) << 4)));
  }
  __syncthreads();                         // ev reads done

  // ---- acc -> et re-layout (bf16, chunk-major) ----
#pragma unroll
  for (int mt = 0; mt < 2; ++mt)
#pragma unroll
    for (int nt = 0; nt < 4; ++nt) {
      int col = wave * 64 + nt * 16 + cl;
      int c8 = col >> 3;
      char* base = (char*)et + c8 * 512 + (col & 7) * 2;
#pragma unroll
      for (int q = 0; q < 4; ++q) {
        int r2 = mt * 16 + rq * 4 + q;
        *(uint16_t*)(base + ((r2 * 16) ^ ((c8 & 3) << 4))) =
            (uint16_t)f2bf(acc[mt][nt][q]);
      }
    }
  __syncthreads();                         // relayout visible

  // ---- gather + silu + residual + store (1 row/thread, 4 chunks) ----
  if (cb == 0 && valid) seg[rg] = gseg;
#pragma unroll
  for (int i = 0; i < 4; ++i) {
    int c8 = cb + 8 * i;
    int sw = (c8 & 3) << 4;
    s16x8 av = *(const s16x8*)((const char*)et + c8 * 512 + ((rr * 16) ^ sw));
    s16x8 ho;
    f32x4 f0, f1;
#pragma unroll
    for (int j = 0; j < 8; ++j) {
      uint32_t xbw = ((const uint32_t*)&gb[i])[j >> 1];
      uint32_t xcw = ((const uint32_t*)&gc[i])[j >> 1];
      float xbf = bf2f((j & 1) ? (xbw >> 16) : xbw);
      float xcf = bf2f((j & 1) ? (xcw >> 16) : xcw);
      float de = bf2f((uint16_t)av[j]) + xbf + xcf;      // b1 folded in xc
      float sig = 1.f / (1.f + __expf(-de));
      float h = bf2f((uint16_t)ev[i][j]) + de * sig;
      if (BF16H) ho[j] = f2bf(h);
      else { if (j < 4) f0[j] = h; else f1[j - 4] = h; }
    }
    if (valid) {
      if (BF16H) {
        *(s16x8*)((uint16_t*)hout + (size_t)rg * 256 + c8 * 8) = ho;
      } else {
        float* hp_ = (float*)hout + (size_t)rg * 256 + c8 * 8;
        *(f32x4*)hp_ = f0; *(f32x4*)(hp_ + 4) = f1;
      }
    }
  }
}

// ------------------------------------------------- segment sums via one-hot MFMA
// sum[g,d] = P[g,r] @ H[r,d], sq[g,d] = P @ (H.^2); P one-hot from seg.
__global__ __launch_bounds__(512, 1) void k_sums_mfma(
    const void* __restrict__ hsrc, const int* __restrict__ seg,
    float* __restrict__ part, int E) {
  __shared__ alignas(16) uint16_t hb[2][32 * 256];   // byte = d*64 + ((r*2)^((d&3)<<4))
  __shared__ alignas(16) int      sg[2][32];
  __shared__ float lcnt[NGRAPH];
  const int tid = threadIdx.x;
  const int lane = tid & 63, wv = tid >> 6;
  const int cl = lane & 15, rq = lane >> 4;
  const int d0 = wv * 32;
  const int sr = tid & 15;          // row-pair: rows sr*2, sr*2+1
  const int d8 = tid >> 4;          // 0..31 -> d-range [d8*8, d8*8+8)

  if (tid < NGRAPH) lcnt[tid] = 0.f;

  f32x4 accS[4][2], accQ[4][2];
#pragma unroll
  for (int gt = 0; gt < 4; ++gt)
#pragma unroll
    for (int dt = 0; dt < 2; ++dt) { accS[gt][dt] = (f32x4)0.f; accQ[gt][dt] = (f32x4)0.f; }

  uint32_t q0[4], q1[4];            // packed bf16 pairs, rows sr*2 / sr*2+1
  int sgv = 0;

  auto loadTile = [&](int rt) {
    const uint16_t* hp = (const uint16_t*)hsrc;
    int r2 = rt + sr * 2;
    u32x4 a = (r2 < E)     ? *(const u32x4*)(hp + (size_t)r2 * 256 + d8 * 8)       : (u32x4)0u;
    u32x4 b = (r2 + 1 < E) ? *(const u32x4*)(hp + (size_t)(r2 + 1) * 256 + d8 * 8) : (u32x4)0u;
#pragma unroll
    for (int i = 0; i < 4; ++i) { q0[i] = a[i]; q1[i] = b[i]; }
    if (tid < 32) sgv = (rt + tid < E) ? seg[rt + tid] : 0;
  };
  auto writeTile = [&](int buf) {
#pragma unroll
    for (int i = 0; i < 4; ++i) {
      int da = d8 * 8 + 2 * i, db = da + 1;
      uint32_t lo = q0[i], hi = q1[i];
      uint32_t w0 = (lo & 0xffffu) | (hi << 16);
      uint32_t w1 = (lo >> 16) | (hi & 0xffff0000u);
      *(uint32_t*)((char*)hb[buf] + da * 64 + ((sr * 4) ^ ((da & 3) << 4))) = w0;
      *(uint32_t*)((char*)hb[buf] + db * 64 + ((sr * 4) ^ ((db & 3) << 4))) = w1;
    }
    if (tid < 32) sg[buf][tid] = sgv;
  };
  auto compute = [&](int buf, int rt) {
    int segv[8];
#pragma unroll
    for (int j = 0; j < 8; ++j) segv[j] = sg[buf][rq * 8 + j];
    s16x8 af[4];
#pragma unroll
    for (int gt = 0; gt < 4; ++gt) {
      int gcol = gt * 16 + cl;
      u32x4 aw;
#pragma unroll
      for (int jp = 0; jp < 4; ++jp)
        aw[jp] = (segv[2 * jp]     == gcol ? 0x3F80u     : 0u)
               | (segv[2 * jp + 1] == gcol ? 0x3F800000u : 0u);
      af[gt] = __builtin_bit_cast(s16x8, aw);
    }
#pragma unroll
    for (int dt = 0; dt < 2; ++dt) {
      int d = d0 + dt * 16 + cl;
      s16x8 bf = *(const s16x8*)((const char*)hb[buf] + d * 64 + ((rq * 16) ^ ((d & 3) << 4)));
      s16x8 qf;
#pragma unroll
      for (int i = 0; i < 8; ++i) {
        float f = __uint_as_float(((uint32_t)(uint16_t)bf[i]) << 16);
        qf[i] = f2bf(f * f);
      }
#pragma unroll
      for (int gt = 0; gt < 4; ++gt) {
        accS[gt][dt] = __builtin_amdgcn_mfma_f32_16x16x32_bf16(af[gt], bf, accS[gt][dt], 0, 0, 0);
        accQ[gt][dt] = __builtin_amdgcn_mfma_f32_16x16x32_bf16(af[gt], qf, accQ[gt][dt], 0, 0, 0);
      }
    }
    if (tid < 32 && rt + tid < E) ds_addf(&lcnt[sg[buf][tid]], 1.f);
  };

  const int STEP = SUMNB * 32;      // 8192 rows per sweep
  int r0 = blockIdx.x * 32;
  if (r0 < E) { loadTile(r0); writeTile(0); }
  __syncthreads();
  int cur = 0;
  while (r0 < E) {
    int rn = r0 + STEP;
    bool more = rn < E;
    if (more) loadTile(rn);         // issue-early: HBM latency hides under MFMA
    compute(cur, r0);
    __syncthreads();
    if (more) { writeTile(cur ^ 1); __syncthreads(); }
    cur ^= 1;
    r0 = rn;
  }
  asm volatile("s_waitcnt lgkmcnt(0)" ::: "memory");   // drain asm ds_add (counts)
  __syncthreads();

  float* pb = part + (size_t)blockIdx.x * PSTRIDE;
#pragma unroll
  for (int gt = 0; gt < 4; ++gt)
#pragma unroll
    for (int dt = 0; dt < 2; ++dt)
#pragma unroll
      for (int qq = 0; qq < 4; ++qq) {
        int g = gt * 16 + rq * 4 + qq;          // C-frag: row=(lane>>4)*4+reg
        int d = d0 + dt * 16 + cl;              //         col=lane&15
        pb[g * 256 + d] = accS[gt][dt][qq];
        pb[NGRAPH * 256 + g * 256 + d] = accQ[gt][dt][qq];
      }
  if (tid < NGRAPH) pb[NGRAPH * 256 * 2 + tid] = lcnt[tid];
}

// ------------------------------------------------- legacy atomic k_sums (fallback)
__global__ __launch_bounds__(512, 1) void k_sums_atomic(const float* __restrict__ h,
                                                        const int* __restrict__ seg,
                                                        float* __restrict__ gsum,
                                                        float* __restrict__ gsq,
                                                        float* __restrict__ gcnt, int E) {
  __shared__ float ls[NGRAPH * 256];      // d-permuted layout
  __shared__ float lq[NGRAPH * 256];
  __shared__ float lc[NGRAPH];
  const int t = threadIdx.x;
  for (int i = t; i < NGRAPH * 256; i += 512) { ls[i] = 0.f; lq[i] = 0.f; }
  if (t < NGRAPH) lc[t] = 0.f;
  __syncthreads();
  const int ro = t >> 5, c = t & 31;
  const int step = gridDim.x * 16;
  for (int r0 = blockIdx.x * 16; r0 < E; r0 += step) {
    int r = r0 + ro;
    if (r < E) {
      int g = seg[r];
      const float* hp = h + (size_t)r * 256 + c * 8;
      if (c == 0) ds_addf(&lc[g], 1.f);
      float* bs = ls + g * 256;
      float* bq = lq + g * 256;
#pragma unroll
      for (int j = 0; j < 8; ++j) {
        int dp = c | (j << 5);
        float v = hp[j];
        ds_addf(&bs[dp], v);
        ds_addf(&bq[dp], v * v);
      }
    }
  }
  asm volatile("s_waitcnt lgkmcnt(0)" ::: "memory");
  __syncthreads();
  for (int i = t; i < NGRAPH * 256; i += 512) {
    unsafeAtomicAdd(&gsum[i], ls[i]);
    unsafeAtomicAdd(&gsq[i], lq[i]);
  }
  if (t < NGRAPH) unsafeAtomicAdd(&gcnt[t], lc[t]);
}

// ------------------------------------------------- per-(g,d) affine tables
// NB>0: reduce NB block-partials (natural layout); NB==0: legacy dperm'd tables
__global__ __launch_bounds__(256) void k_stats(const float* __restrict__ part, int NB,
                                               const float* __restrict__ gsum,
                                               const float* __restrict__ gsq,
                                               const float* __restrict__ gcnt,
                                               const float* __restrict__ w,
                                               const float* __restrict__ b,
                                               const float* __restrict__ ms,
                                               float* __restrict__ atab,
                                               float* __restrict__ ctab) {
  int g = blockIdx.x, d = threadIdx.x;
  float s = 0.f, q = 0.f, cn = 0.f;
  if (NB > 0) {
    const float* ps = part + g * 256 + d;
    const float* pq = part + NGRAPH * 256 + g * 256 + d;
    const float* pc = part + NGRAPH * 256 * 2 + g;
#pragma unroll 4
    for (int bb = 0; bb < NB; ++bb) {
      size_t o = (size_t)bb * PSTRIDE;
      s  += ps[o];
      q  += pq[o];
      cn += pc[o];
    }
  } else {
    int dp = dperm(d);
    s = gsum[g * 256 + dp]; q = gsq[g * 256 + dp]; cn = gcnt[g];
  }
  float cnt = fmaxf(cn, 1.f);
  float m   = s / cnt;
  float msq = q / cnt;
  float sc  = ms[d];
  float var = msq - m * m * sc * (2.f - sc);
  float rstd = rsqrtf(fmaxf(var, 0.f) + 1e-5f);
  float A = w[d] * rstd;
  atab[g * 256 + d] = A;
  ctab[g * 256 + d] = b[d] - A * sc * m;
}

// ------------------------------------------------- apply: out = A[g]*h + C[g]
template <bool BF16H>
__global__ __launch_bounds__(256) void k_apply(const void* __restrict__ h,
                                               const int* __restrict__ seg,
                                               const float* __restrict__ atab,
                                               const float* __restrict__ ctab,
                                               float* __restrict__ out, int E) {
  const long long total = (long long)E * 32;
  for (long long i = (long long)blockIdx.x * 256 + threadIdx.x; i < total;
       i += (long long)gridDim.x * 256) {
    int row = (int)(i >> 5);
    int c8 = ((int)i & 31) * 8;
    int g = seg[row];
    const f32x4* Ap = (const f32x4*)(atab + g * 256 + c8);
    const f32x4* Cp = (const f32x4*)(ctab + g * 256 + c8);
    f32x4 A0 = Ap[0], A1 = Ap[1], C0 = Cp[0], C1 = Cp[1];
    f32x4 h0, h1;
    if (BF16H) {
      u32x4 p = *(const u32x4*)((const uint16_t*)h + (size_t)row * 256 + c8);
      h0[0] = bf2f(p[0]); h0[1] = bf2f(p[0] >> 16);
      h0[2] = bf2f(p[1]); h0[3] = bf2f(p[1] >> 16);
      h1[0] = bf2f(p[2]); h1[1] = bf2f(p[2] >> 16);
      h1[2] = bf2f(p[3]); h1[3] = bf2f(p[3] >> 16);
    } else {
      const f32x4* hp = (const f32x4*)((const float*)h + (size_t)row * 256 + c8);
      h0 = hp[0]; h1 = hp[1];
    }
    f32x4 o0 = A0 * h0 + C0, o1 = A1 * h1 + C1;
    f32x4* op = (f32x4*)(out + (size_t)row * 256 + c8);
    op[0] = o0; op[1] = o1;
  }
}

// ----------------------------------------------------------------- launch
extern "C" void kernel_launch(void* const* d_in, const int* in_sizes, int n_in,
                              void* d_out, int out_size, void* d_ws, size_t ws_size,
                              hipStream_t stream) {
  const float* x     = (const float*)d_in[0];
  const float* e     = (const float*)d_in[1];
  const int*   batch = (const int*)d_in[2];
  const int*   eidx  = (const int*)d_in[3];
  const float* W1    = (const float*)d_in[4];
  const float* b1    = (const float*)d_in[5];
  const float* gw    = (const float*)d_in[6];
  const float* gb    = (const float*)d_in[7];
  const float* gms   = (const float*)d_in[8];
  const int NV = in_sizes[0] / 256;
  const int E  = in_sizes[1] / 256;
  const int* srcI = eidx;
  const int* dstI = eidx + E;

  char* ws = (char*)d_ws;
  size_t off = 0;
  auto alloc = [&](size_t bytes) {
    size_t o = off;
    off += (bytes + 255) & ~(size_t)255;
    return o;
  };
  size_t o_wta  = alloc(256 * 256 * 2);
  size_t o_wtbc = alloc(512 * 256 * 2);
  size_t o_gsum = alloc(NGRAPH * 256 * 4);
  size_t o_gsq  = alloc(NGRAPH * 256 * 4);
  size_t o_gcnt = alloc(256);
  size_t o_atab = alloc(NGRAPH * 256 * 4);
  size_t o_ctab = alloc(NGRAPH * 256 * 4);
  size_t o_seg  = alloc((size_t)E * 4);
  size_t o_xbc  = alloc((size_t)NV * 512 * 2);     // bf16
  size_t o_h    = alloc((size_t)E * 256 * 2);
  const bool fast = ws_size >= off;   // h (bf16) fits in ws? else stage f32 in d_out

  uint16_t* wta  = (uint16_t*)(ws + o_wta);
  uint16_t* wtbc = (uint16_t*)(ws + o_wtbc);
  float* gsum = (float*)(ws + o_gsum);
  float* gsq  = (float*)(ws + o_gsq);
  float* gcnt = (float*)(ws + o_gcnt);
  float* atab = (float*)(ws + o_atab);
  float* ctab = (float*)(ws + o_ctab);
  int*   seg  = (int*)(ws + o_seg);
  uint16_t* xbc = (uint16_t*)(ws + o_xbc);
  void*  hbuf = fast ? (void*)(ws + o_h) : d_out;
  // fast path: block-partials at the START of d_out (33.6 MB << 164 MB);
  // consumed by k_stats, then fully overwritten by k_apply. Deterministic.
  float* part = fast ? (float*)d_out : nullptr;
  const int NB = fast ? SUMNB : 0;

  k_wconv<<<768, 256, 0, stream>>>(W1, wta, wtbc);
  k_nodegemm<<<(NV + 31) / 32, 256, 0, stream>>>(x, wtbc, b1, xbc, NV);
  if (fast) {
    k_edgegemm<true><<<(E + 31) / 32, 256, 0, stream>>>(e, wta, xbc, srcI, dstI,
                                                        batch, hbuf, seg, E);
    k_sums_mfma<<<SUMNB, 512, 0, stream>>>(hbuf, seg, part, E);
  } else {
    const int nz = NGRAPH * 256 * 2 + 64;   // gsum|gsq|gcnt contiguous
    k_zero<<<(nz + 255) / 256, 256, 0, stream>>>(gsum, nz);
    k_edgegemm<false><<<(E + 31) / 32, 256, 0, stream>>>(e, wta, xbc, srcI, dstI,
                                                         batch, hbuf, seg, E);
    k_sums_atomic<<<256, 512, 0, stream>>>((const float*)hbuf, seg, gsum, gsq, gcnt, E);
  }
  k_stats<<<NGRAPH, 256, 0, stream>>>(part, NB, gsum, gsq, gcnt, gw, gb, gms, atab, ctab);
  if (fast)
    k_apply<true><<<2048, 256, 0, stream>>>(hbuf, seg, atab, ctab, (float*)d_out, E);
  else
    k_apply<false><<<2048, 256, 0, stream>>>(hbuf, seg, atab, ctab, (float*)d_out, E);
}

// Round 14
// 222.608 us; speedup vs baseline: 1.0834x; 1.0834x over previous
//
#include <hip/hip_runtime.h>
#include <hip/hip_bf16.h>
#include <stdint.h>

// GINE edge layer on MI355X:
//   de = concat([e, x[src], x[dst]]) @ W1 + b1 ; de = silu(de); h = e + de
//   out = GraphNorm(h, seg=batch[src])  (per-graph mean/var, ms-scaled mean)
// Decomposition: concat@W1 = e@W1a + xb[src] + xc[dst], xb/xc per NODE.
// GraphNorm one-pass: var = E[h^2] - m^2*ms*(2-ms); out = A[g,d]*h + C[g,d].
// R2/R3: LDS fp-atomic RMW serializes -> MFMA one-hot segsum.
// R5/R6: e re-read killed; gather chain vectorized (bf16 xbc + b1 fold).
// R7-R13: edgegemm structure space exhausted (7 variants, 99-153us):
//   R10 persistent+resident-W (99us) is the floor -> REVERTED to it.
//   R11/R12 fusion fails (1-blk/CU = serial phases); R13 W-from-L2 fails
//   (B-frag L2 latency in MFMA dep chain).
// R14: k_sums_mfma 1 blk/CU (25% occ cap, 2.3 TB/s on 82MB) -> grid 512 +
//   __launch_bounds__(512,4) = 2 blk/CU; NB=512 partials (k_stats +6us).

typedef float   f32x4 __attribute__((ext_vector_type(4)));
typedef short   s16x8 __attribute__((ext_vector_type(8)));
typedef uint32_t u32x4 __attribute__((ext_vector_type(4)));
typedef int     i32x4 __attribute__((ext_vector_type(4)));

#define NGRAPH 64
#define SUMNB  512                      // k_sums grid (2 blocks/CU)
#define PSTRIDE (NGRAPH * 256 * 2 + NGRAPH)   // floats per block-partial: sum|sq|cnt

__device__ __forceinline__ void gld16(const void* g, void* l) {
  __builtin_amdgcn_global_load_lds(
      (const __attribute__((address_space(1))) uint32_t*)g,
      (__attribute__((address_space(3))) uint32_t*)l, 16, 0, 0);
}

// native LDS f32 add, no return (tiny per-row counts / fallback only)
__device__ __forceinline__ void ds_addf(float* p, float v) {
  asm volatile("ds_add_f32 %0, %1"
               :: "v"((__attribute__((address_space(3))) float*)p), "v"(v));
}

__device__ __forceinline__ short f2bf(float f) {
  __bf16 b = (__bf16)f;                       // RTNE
  return __builtin_bit_cast(short, b);
}
__device__ __forceinline__ float bf2f(uint32_t u) {
  return __uint_as_float((u & 0xffffu) << 16);
}

// legacy-path permuted d-index (atomic fallback kernel only)
__device__ __forceinline__ int dperm(int d) { return (d >> 3) | ((d & 7) << 5); }

// ---------------------------------------------------------------- zero tables
__global__ __launch_bounds__(256) void k_zero(float* p, int n) {
  int i = blockIdx.x * 256 + threadIdx.x;
  if (i < n) p[i] = 0.f;
}

// ------------------------------------------- W1 f32 [768][256] -> transposed bf16
__global__ __launch_bounds__(256) void k_wconv(const float* __restrict__ W1,
                                               uint16_t* __restrict__ wta,
                                               uint16_t* __restrict__ wtbc) {
  int k = blockIdx.x;            // 0..767
  int n = threadIdx.x;           // 0..255
  uint16_t v = (uint16_t)f2bf(W1[k * 256 + n]);
  if (k < 256)      wta[n * 256 + k] = v;
  else if (k < 512) wtbc[n * 256 + (k - 256)] = v;
  else              wtbc[(n + 256) * 256 + (k - 512)] = v;
}

// ------------------------------------------------- node GEMM: xbc = x @ Wbc (bf16 out)
// xbc[node][0..256) = x@W1b ; xbc[node][256..512) = x@W1c + b1  (b1 folded)
__global__ __launch_bounds__(256, 2) void k_nodegemm(const float* __restrict__ x,
                                                     const uint16_t* __restrict__ wtbc,
                                                     const float* __restrict__ b1,
                                                     uint16_t* __restrict__ xbc, int NV) {
  __shared__ float    xt[32 * 64];
  __shared__ uint16_t wtb[512 * 64];
  const int tid = threadIdx.x, wave = tid >> 6, lane = tid & 63;
  const int m0 = blockIdx.x * 32;
  const int cl = lane & 15, rq = lane >> 4;

  f32x4 acc[2][8];
#pragma unroll
  for (int a = 0; a < 2; ++a)
#pragma unroll
    for (int b = 0; b < 8; ++b) acc[a][b] = (f32x4)0.f;

  for (int kk = 0; kk < 4; ++kk) {
    const int k0 = kk * 64;
#pragma unroll
    for (int ii = 0; ii < 2; ++ii) {
      int i = wave * 2 + ii;
      int row = i * 4 + rq;
      int k8 = cl ^ (row & 15);
      int grow = m0 + row; if (grow > NV - 1) grow = NV - 1;
      gld16((const char*)x + ((size_t)grow * 256 + k0) * 4 + k8 * 16,
            (char*)xt + i * 1024);
    }
#pragma unroll
    for (int ii = 0; ii < 16; ++ii) {
      int i = wave * 16 + ii;
      int n = i * 8 + (lane >> 3);
      int k8 = (lane & 7) ^ (n & 7);
      gld16((const char*)wtbc + ((size_t)n * 256 + k0) * 2 + k8 * 16,
            (char*)wtb + i * 1024);
    }
    __syncthreads();
#pragma unroll
    for (int ks = 0; ks < 2; ++ks) {
      s16x8 a[2], b[8];
#pragma unroll
      for (int mt = 0; mt < 2; ++mt) {
        int row = mt * 16 + cl;
        int sbase = ks * 8 + rq * 2;
        int sw = (row & 15) << 4;
        f32x4 f0 = *(const f32x4*)((const char*)xt + row * 256 + (((sbase    ) << 4) ^ sw));
        f32x4 f1 = *(const f32x4*)((const char*)xt + row * 256 + (((sbase + 1) << 4) ^ sw));
        s16x8 t;
        t[0] = f2bf(f0[0]); t[1] = f2bf(f0[1]); t[2] = f2bf(f0[2]); t[3] = f2bf(f0[3]);
        t[4] = f2bf(f1[0]); t[5] = f2bf(f1[1]); t[6] = f2bf(f1[2]); t[7] = f2bf(f1[3]);
        a[mt] = t;
      }
#pragma unroll
      for (int nt = 0; nt < 8; ++nt) {
        int n = wave * 128 + nt * 16 + cl;
        int byt = n * 128 + ((((ks * 4 + rq)) << 4) ^ ((n & 7) << 4));
        b[nt] = *(const s16x8*)((const char*)wtb + byt);
      }
#pragma unroll
      for (int mt = 0; mt < 2; ++mt)
#pragma unroll
        for (int nt = 0; nt < 8; ++nt)
          acc[mt][nt] = __builtin_amdgcn_mfma_f32_16x16x32_bf16(a[mt], b[nt], acc[mt][nt], 0, 0, 0);
    }
    __syncthreads();
  }
  float b1v[8];
#pragma unroll
  for (int nt = 0; nt < 8; ++nt) {
    int col = wave * 128 + nt * 16 + cl;
    b1v[nt] = (col >= 256) ? b1[col - 256] : 0.f;
  }
#pragma unroll
  for (int mt = 0; mt < 2; ++mt)
#pragma unroll
    for (int q = 0; q < 4; ++q) {
      int row = m0 + mt * 16 + rq * 4 + q;
      if (row < NV) {
#pragma unroll
        for (int nt = 0; nt < 8; ++nt) {
          int col = wave * 128 + nt * 16 + cl;
          xbc[(size_t)row * 512 + col] = (uint16_t)f2bf(acc[mt][nt][q] + b1v[nt]);
        }
      }
    }
}

// ------------------------------------------------- edge GEMM + epilogue (persistent)
// R10 structure (best of 7 variants, 99us): grid<=256 (1 blk/CU), 512 thr =
// 8 waves (2 row-grp x 4 col-grp), grid-stride over 64-row tiles.
// W1a^T RESIDENT in LDS 128 KB: byte = n*512 + ((k8^(n&7))<<4).
// et 32 KB: e-tile (chunk-major) reused as relayout buffer per tile.
template <bool BF16H>
__global__ __launch_bounds__(512, 2) void k_edgegemm(
    const float* __restrict__ e, const uint16_t* __restrict__ wta,
    const uint16_t* __restrict__ xbc,
    const int* __restrict__ srcI, const int* __restrict__ dstI,
    const int* __restrict__ batch, void* __restrict__ hout,
    int* __restrict__ seg, int E, int ntiles) {
  __shared__ alignas(16) uint16_t wl[256 * 256];  // 128 KB resident W1a^T
  __shared__ alignas(16) uint16_t et[64 * 256];   // 32 KB e-tile / relayout
  const int tid = threadIdx.x, wave = tid >> 6, lane = tid & 63;
  const int wr = wave >> 2, wc = wave & 3;
  const int cl = lane & 15, rq = lane >> 4;
  const int rr = tid >> 3;                 // 0..63 (row in tile)
  const int cb = tid & 7;                  // chunk base

  // ---- stage resident W once ----
#pragma unroll
  for (int i = 0; i < 16; ++i) {
    int n = i * 16 + (tid >> 5);
    int k8 = (tid & 31) ^ (n & 7);
    gld16((const char*)wta + ((size_t)n * 256 + k8 * 8) * 2,
          (char*)wl + i * 8192 + tid * 16);
  }

  f32x4 er[8];                             // e prefetch: 4 chunks x 2 f32x4
  auto loadE = [&](int t) {
    int r = t * 64 + rr; int rc = r < E ? r : E - 1;
    const float* ep = e + (size_t)rc * 256;
#pragma unroll
    for (int i = 0; i < 4; ++i) {
      int s = cb + 8 * i;
      er[2 * i]     = *(const f32x4*)(ep + s * 8);
      er[2 * i + 1] = *(const f32x4*)(ep + s * 8 + 4);
    }
  };
  auto writeE = [&]() {
#pragma unroll
    for (int i = 0; i < 4; ++i) {
      int s = cb + 8 * i;
      f32x4 f0 = er[2 * i], f1 = er[2 * i + 1];
      s16x8 t;
      t[0] = f2bf(f0[0]); t[1] = f2bf(f0[1]); t[2] = f2bf(f0[2]); t[3] = f2bf(f0[3]);
      t[4] = f2bf(f1[0]); t[5] = f2bf(f1[1]); t[6] = f2bf(f1[2]); t[7] = f2bf(f1[3]);
      *(s16x8*)((char*)et + s * 1024 + ((rr * 16) ^ ((s & 3) << 4))) = t;
    }
  };

  int t = blockIdx.x;
  const int G = gridDim.x;
  if (t < ntiles) { loadE(t); writeE(); }
  __syncthreads();                          // W staged + e(tile0) visible

  for (; t < ntiles; t += G) {
    const int tn = t + G;
    // idx for current tile
    int r = t * 64 + rr;
    bool valid = r < E;
    int rc = valid ? r : E - 1;
    int sA = srcI[rc], dA = dstI[rc];
    int gseg = batch[sA];
    if (tn < ntiles) loadE(tn);             // prefetch next e (hidden under K-loop)

    // ---- barrier-free K-loop over resident W ----
    f32x4 acc[2][4];
#pragma unroll
    for (int a = 0; a < 2; ++a)
#pragma unroll
      for (int b = 0; b < 4; ++b) acc[a][b] = (f32x4)0.f;
#pragma unroll
    for (int kk = 0; kk < 8; ++kk) {
      s16x8 a[2], b[4];
#pragma unroll
      for (int mt = 0; mt < 2; ++mt) {
        int row = wr * 32 + mt * 16 + cl;
        int c8s = kk * 4 + rq;
        a[mt] = *(const s16x8*)((const char*)et + c8s * 1024 + ((row * 16) ^ (rq << 4)));
      }
#pragma unroll
      for (int nt = 0; nt < 4; ++nt) {
        int n = wc * 64 + nt * 16 + cl;
        int kc = kk * 4 + rq;
        b[nt] = *(const s16x8*)((const char*)wl + n * 512 + ((kc ^ (n & 7)) << 4));
      }
#pragma unroll
      for (int mt = 0; mt < 2; ++mt)
#pragma unroll
        for (int nt = 0; nt < 4; ++nt)
          acc[mt][nt] = __builtin_amdgcn_mfma_f32_16x16x32_bf16(a[mt], b[nt], acc[mt][nt], 0, 0, 0);
    }

    // ---- gathers for current tile (L3; consumed after 2 barriers) ----
    u32x4 gb[4], gc[4];
#pragma unroll
    for (int i = 0; i < 4; ++i) {
      int c8 = cb + 8 * i;
      gb[i] = *(const u32x4*)(xbc + (size_t)sA * 512 + c8 * 8);
      gc[i] = *(const u32x4*)(xbc + (size_t)dA * 512 + 256 + c8 * 8);
    }
    // ---- e residual out of et before relayout clobbers it ----
    s16x8 ev[4];
#pragma unroll
    for (int i = 0; i < 4; ++i) {
      int c8 = cb + 8 * i;
      ev[i] = *(const s16x8*)((const char*)et + c8 * 1024 + ((rr * 16) ^ ((c8 & 3) << 4)));
    }
    __syncthreads();

    // ---- relayout acc -> et (bf16, chunk-major) ----
#pragma unroll
    for (int mt = 0; mt < 2; ++mt)
#pragma unroll
      for (int nt = 0; nt < 4; ++nt) {
        int col = wc * 64 + nt * 16 + cl;
        int c8 = col >> 3;
        char* base = (char*)et + c8 * 1024 + (col & 7) * 2;
#pragma unroll
        for (int q = 0; q < 4; ++q) {
          int row = wr * 32 + mt * 16 + rq * 4 + q;
          *(uint16_t*)(base + ((row * 16) ^ ((c8 & 3) << 4))) =
              (uint16_t)f2bf(acc[mt][nt][q]);
        }
      }
    __syncthreads();

    // ---- combine + store ----
    if (cb == 0 && valid) seg[r] = gseg;
#pragma unroll
    for (int i = 0; i < 4; ++i) {
      int c8 = cb + 8 * i;
      int sw = (c8 & 3) << 4;
      s16x8 av = *(const s16x8*)((const char*)et + c8 * 1024 + ((rr * 16) ^ sw));
      s16x8 ho;
      f32x4 f0, f1;
#pragma unroll
      for (int j = 0; j < 8; ++j) {
        uint32_t xbw = ((const uint32_t*)&gb[i])[j >> 1];
        uint32_t xcw = ((const uint32_t*)&gc[i])[j >> 1];
        float xbf = bf2f((j & 1) ? (xbw >> 16) : xbw);
        float xcf = bf2f((j & 1) ? (xcw >> 16) : xcw);
        float de = bf2f((uint16_t)av[j]) + xbf + xcf;      // b1 folded in xc
        float sig = 1.f / (1.f + __expf(-de));
        float h = bf2f((uint16_t)ev[i][j]) + de * sig;
        if (BF16H) ho[j] = f2bf(h);
        else { if (j < 4) f0[j] = h; else f1[j - 4] = h; }
      }
      if (valid) {
        if (BF16H) {
          *(s16x8*)((uint16_t*)hout + (size_t)r * 256 + c8 * 8) = ho;
        } else {
          float* hp_ = (float*)hout + (size_t)r * 256 + c8 * 8;
          *(f32x4*)hp_ = f0; *(f32x4*)(hp_ + 4) = f1;
        }
      }
    }
    __syncthreads();                        // et reads done before next e write

    if (tn < ntiles) writeE();              // stage e for next tile
    __syncthreads();
  }
}

// ------------------------------------------------- segment sums via one-hot MFMA
// sum[g,d] = P[g,r] @ H[r,d], sq[g,d] = P @ (H.^2); P one-hot from seg.
// R14: 2 blocks/CU (grid 512, launch_bounds(512,4)) -- was 1 blk/CU, 25% occ.
__global__ __launch_bounds__(512, 4) void k_sums_mfma(
    const void* __restrict__ hsrc, const int* __restrict__ seg,
    float* __restrict__ part, int E) {
  __shared__ alignas(16) uint16_t hb[2][32 * 256];   // byte = d*64 + ((r*2)^((d&3)<<4))
  __shared__ alignas(16) int      sg[2][32];
  __shared__ float lcnt[NGRAPH];
  const int tid = threadIdx.x;
  const int lane = tid & 63, wv = tid >> 6;
  const int cl = lane & 15, rq = lane >> 4;
  const int d0 = wv * 32;
  const int sr = tid & 15;          // row-pair: rows sr*2, sr*2+1
  const int d8 = tid >> 4;          // 0..31 -> d-range [d8*8, d8*8+8)

  if (tid < NGRAPH) lcnt[tid] = 0.f;

  f32x4 accS[4][2], accQ[4][2];
#pragma unroll
  for (int gt = 0; gt < 4; ++gt)
#pragma unroll
    for (int dt = 0; dt < 2; ++dt) { accS[gt][dt] = (f32x4)0.f; accQ[gt][dt] = (f32x4)0.f; }

  uint32_t q0[4], q1[4];            // packed bf16 pairs, rows sr*2 / sr*2+1
  int sgv = 0;

  auto loadTile = [&](int rt) {
    const uint16_t* hp = (const uint16_t*)hsrc;
    int r2 = rt + sr * 2;
    u32x4 a = (r2 < E)     ? *(const u32x4*)(hp + (size_t)r2 * 256 + d8 * 8)       : (u32x4)0u;
    u32x4 b = (r2 + 1 < E) ? *(const u32x4*)(hp + (size_t)(r2 + 1) * 256 + d8 * 8) : (u32x4)0u;
#pragma unroll
    for (int i = 0; i < 4; ++i) { q0[i] = a[i]; q1[i] = b[i]; }
    if (tid < 32) sgv = (rt + tid < E) ? seg[rt + tid] : 0;
  };
  auto writeTile = [&](int buf) {
#pragma unroll
    for (int i = 0; i < 4; ++i) {
      int da = d8 * 8 + 2 * i, db = da + 1;
      uint32_t lo = q0[i], hi = q1[i];
      uint32_t w0 = (lo & 0xffffu) | (hi << 16);
      uint32_t w1 = (lo >> 16) | (hi & 0xffff0000u);
      *(uint32_t*)((char*)hb[buf] + da * 64 + ((sr * 4) ^ ((da & 3) << 4))) = w0;
      *(uint32_t*)((char*)hb[buf] + db * 64 + ((sr * 4) ^ ((db & 3) << 4))) = w1;
    }
    if (tid < 32) sg[buf][tid] = sgv;
  };
  auto compute = [&](int buf, int rt) {
    i32x4 s01 = *(const i32x4*)&sg[buf][rq * 8];
    i32x4 s23 = *(const i32x4*)&sg[buf][rq * 8 + 4];
    int segv[8] = {s01[0], s01[1], s01[2], s01[3], s23[0], s23[1], s23[2], s23[3]};
    s16x8 af[4];
#pragma unroll
    for (int gt = 0; gt < 4; ++gt) {
      int gcol = gt * 16 + cl;
      u32x4 aw;
#pragma unroll
      for (int jp = 0; jp < 4; ++jp)
        aw[jp] = (segv[2 * jp]     == gcol ? 0x3F80u     : 0u)
               | (segv[2 * jp + 1] == gcol ? 0x3F800000u : 0u);
      af[gt] = __builtin_bit_cast(s16x8, aw);
    }
#pragma unroll
    for (int dt = 0; dt < 2; ++dt) {
      int d = d0 + dt * 16 + cl;
      s16x8 bf = *(const s16x8*)((const char*)hb[buf] + d * 64 + ((rq * 16) ^ ((d & 3) << 4)));
      s16x8 qf;
#pragma unroll
      for (int i = 0; i < 8; ++i) {
        float f = __uint_as_float(((uint32_t)(uint16_t)bf[i]) << 16);
        qf[i] = f2bf(f * f);
      }
#pragma unroll
      for (int gt = 0; gt < 4; ++gt) {
        accS[gt][dt] = __builtin_amdgcn_mfma_f32_16x16x32_bf16(af[gt], bf, accS[gt][dt], 0, 0, 0);
        accQ[gt][dt] = __builtin_amdgcn_mfma_f32_16x16x32_bf16(af[gt], qf, accQ[gt][dt], 0, 0, 0);
      }
    }
    if (tid < 32 && rt + tid < E) ds_addf(&lcnt[sg[buf][tid]], 1.f);
  };

  const int STEP = SUMNB * 32;      // 16384 rows per sweep
  int r0 = blockIdx.x * 32;
  if (r0 < E) { loadTile(r0); writeTile(0); }
  __syncthreads();
  int cur = 0;
  while (r0 < E) {
    int rn = r0 + STEP;
    bool more = rn < E;
    if (more) loadTile(rn);         // issue-early: HBM latency hides under MFMA
    compute(cur, r0);
    __syncthreads();
    if (more) { writeTile(cur ^ 1); __syncthreads(); }
    cur ^= 1;
    r0 = rn;
  }
  asm volatile("s_waitcnt lgkmcnt(0)" ::: "memory");   // drain asm ds_add (counts)
  __syncthreads();

  float* pb = part + (size_t)blockIdx.x * PSTRIDE;
#pragma unroll
  for (int gt = 0; gt < 4; ++gt)
#pragma unroll
    for (int dt = 0; dt < 2; ++dt)
#pragma unroll
      for (int qq = 0; qq < 4; ++qq) {
        int g = gt * 16 + rq * 4 + qq;          // C-frag: row=(lane>>4)*4+reg
        int d = d0 + dt * 16 + cl;              //         col=lane&15
        pb[g * 256 + d] = accS[gt][dt][qq];
        pb[NGRAPH * 256 + g * 256 + d] = accQ[gt][dt][qq];
      }
  if (tid < NGRAPH) pb[NGRAPH * 256 * 2 + tid] = lcnt[tid];
}

// ------------------------------------------------- legacy atomic k_sums (fallback)
__global__ __launch_bounds__(512, 1) void k_sums_atomic(const float* __restrict__ h,
                                                        const int* __restrict__ seg,
                                                        float* __restrict__ gsum,
                                                        float* __restrict__ gsq,
                                                        float* __restrict__ gcnt, int E) {
  __shared__ float ls[NGRAPH * 256];      // d-permuted layout
  __shared__ float lq[NGRAPH * 256];
  __shared__ float lc[NGRAPH];
  const int t = threadIdx.x;
  for (int i = t; i < NGRAPH * 256; i += 512) { ls[i] = 0.f; lq[i] = 0.f; }
  if (t < NGRAPH) lc[t] = 0.f;
  __syncthreads();
  const int ro = t >> 5, c = t & 31;
  const int step = gridDim.x * 16;
  for (int r0 = blockIdx.x * 16; r0 < E; r0 += step) {
    int r = r0 + ro;
    if (r < E) {
      int g = seg[r];
      const float* hp = h + (size_t)r * 256 + c * 8;
      if (c == 0) ds_addf(&lc[g], 1.f);
      float* bs = ls + g * 256;
      float* bq = lq + g * 256;
#pragma unroll
      for (int j = 0; j < 8; ++j) {
        int dp = c | (j << 5);
        float v = hp[j];
        ds_addf(&bs[dp], v);
        ds_addf(&bq[dp], v * v);
      }
    }
  }
  asm volatile("s_waitcnt lgkmcnt(0)" ::: "memory");
  __syncthreads();
  for (int i = t; i < NGRAPH * 256; i += 512) {
    unsafeAtomicAdd(&gsum[i], ls[i]);
    unsafeAtomicAdd(&gsq[i], lq[i]);
  }
  if (t < NGRAPH) unsafeAtomicAdd(&gcnt[t], lc[t]);
}

// ------------------------------------------------- per-(g,d) affine tables
// NB>0: reduce NB block-partials (natural layout); NB==0: legacy dperm'd tables
__global__ __launch_bounds__(256) void k_stats(const float* __restrict__ part, int NB,
                                               const float* __restrict__ gsum,
                                               const float* __restrict__ gsq,
                                               const float* __restrict__ gcnt,
                                               const float* __restrict__ w,
                                               const float* __restrict__ b,
                                               const float* __restrict__ ms,
                                               float* __restrict__ atab,
                                               float* __restrict__ ctab) {
  int g = blockIdx.x, d = threadIdx.x;
  float s = 0.f, q = 0.f, cn = 0.f;
  if (NB > 0) {
    const float* ps = part + g * 256 + d;
    const float* pq = part + NGRAPH * 256 + g * 256 + d;
    const float* pc = part + NGRAPH * 256 * 2 + g;
#pragma unroll 4
    for (int bb = 0; bb < NB; ++bb) {
      size_t o = (size_t)bb * PSTRIDE;
      s  += ps[o];
      q  += pq[o];
      cn += pc[o];
    }
  } else {
    int dp = dperm(d);
    s = gsum[g * 256 + dp]; q = gsq[g * 256 + dp]; cn = gcnt[g];
  }
  float cnt = fmaxf(cn, 1.f);
  float m   = s / cnt;
  float msq = q / cnt;
  float sc  = ms[d];
  float var = msq - m * m * sc * (2.f - sc);
  float rstd = rsqrtf(fmaxf(var, 0.f) + 1e-5f);
  float A = w[d] * rstd;
  atab[g * 256 + d] = A;
  ctab[g * 256 + d] = b[d] - A * sc * m;
}

// ------------------------------------------------- apply: out = A[g]*h + C[g]
template <bool BF16H>
__global__ __launch_bounds__(256) void k_apply(const void* __restrict__ h,
                                               const int* __restrict__ seg,
                                               const float* __restrict__ atab,
                                               const float* __restrict__ ctab,
                                               float* __restrict__ out, int E) {
  const long long total = (long long)E * 32;
  for (long long i = (long long)blockIdx.x * 256 + threadIdx.x; i < total;
       i += (long long)gridDim.x * 256) {
    int row = (int)(i >> 5);
    int c8 = ((int)i & 31) * 8;
    int g = seg[row];
    const f32x4* Ap = (const f32x4*)(atab + g * 256 + c8);
    const f32x4* Cp = (const f32x4*)(ctab + g * 256 + c8);
    f32x4 A0 = Ap[0], A1 = Ap[1], C0 = Cp[0], C1 = Cp[1];
    f32x4 h0, h1;
    if (BF16H) {
      u32x4 p = *(const u32x4*)((const uint16_t*)h + (size_t)row * 256 + c8);
      h0[0] = bf2f(p[0]); h0[1] = bf2f(p[0] >> 16);
      h0[2] = bf2f(p[1]); h0[3] = bf2f(p[1] >> 16);
      h1[0] = bf2f(p[2]); h1[1] = bf2f(p[2] >> 16);
      h1[2] = bf2f(p[3]); h1[3] = bf2f(p[3] >> 16);
    } else {
      const f32x4* hp = (const f32x4*)((const float*)h + (size_t)row * 256 + c8);
      h0 = hp[0]; h1 = hp[1];
    }
    f32x4 o0 = A0 * h0 + C0, o1 = A1 * h1 + C1;
    f32x4* op = (f32x4*)(out + (size_t)row * 256 + c8);
    op[0] = o0; op[1] = o1;
  }
}

// ----------------------------------------------------------------- launch
extern "C" void kernel_launch(void* const* d_in, const int* in_sizes, int n_in,
                              void* d_out, int out_size, void* d_ws, size_t ws_size,
                              hipStream_t stream) {
  const float* x     = (const float*)d_in[0];
  const float* e     = (const float*)d_in[1];
  const int*   batch = (const int*)d_in[2];
  const int*   eidx  = (const int*)d_in[3];
  const float* W1    = (const float*)d_in[4];
  const float* b1    = (const float*)d_in[5];
  const float* gw    = (const float*)d_in[6];
  const float* gb    = (const float*)d_in[7];
  const float* gms   = (const float*)d_in[8];
  const int NV = in_sizes[0] / 256;
  const int E  = in_sizes[1] / 256;
  const int* srcI = eidx;
  const int* dstI = eidx + E;

  char* ws = (char*)d_ws;
  size_t off = 0;
  auto alloc = [&](size_t bytes) {
    size_t o = off;
    off += (bytes + 255) & ~(size_t)255;
    return o;
  };
  size_t o_wta  = alloc(256 * 256 * 2);
  size_t o_wtbc = alloc(512 * 256 * 2);
  size_t o_gsum = alloc(NGRAPH * 256 * 4);
  size_t o_gsq  = alloc(NGRAPH * 256 * 4);
  size_t o_gcnt = alloc(256);
  size_t o_atab = alloc(NGRAPH * 256 * 4);
  size_t o_ctab = alloc(NGRAPH * 256 * 4);
  size_t o_seg  = alloc((size_t)E * 4);
  size_t o_xbc  = alloc((size_t)NV * 512 * 2);     // bf16
  size_t o_h    = alloc((size_t)E * 256 * 2);
  const bool fast = ws_size >= off;   // h (bf16) fits in ws? else stage f32 in d_out

  uint16_t* wta  = (uint16_t*)(ws + o_wta);
  uint16_t* wtbc = (uint16_t*)(ws + o_wtbc);
  float* gsum = (float*)(ws + o_gsum);
  float* gsq  = (float*)(ws + o_gsq);
  float* gcnt = (float*)(ws + o_gcnt);
  float* atab = (float*)(ws + o_atab);
  float* ctab = (float*)(ws + o_ctab);
  int*   seg  = (int*)(ws + o_seg);
  uint16_t* xbc = (uint16_t*)(ws + o_xbc);
  void*  hbuf = fast ? (void*)(ws + o_h) : d_out;
  // fast path: block-partials at the START of d_out (512*131KB = 67MB << 164 MB);
  // consumed by k_stats, then fully overwritten by k_apply. Deterministic.
  float* part = fast ? (float*)d_out : nullptr;
  const int NB = fast ? SUMNB : 0;

  const int ntiles = (E + 63) / 64;
  const int egrid = ntiles < 256 ? ntiles : 256;

  k_wconv<<<768, 256, 0, stream>>>(W1, wta, wtbc);
  k_nodegemm<<<(NV + 31) / 32, 256, 0, stream>>>(x, wtbc, b1, xbc, NV);
  if (fast) {
    k_edgegemm<true><<<egrid, 512, 0, stream>>>(e, wta, xbc, srcI, dstI,
                                                batch, hbuf, seg, E, ntiles);
    k_sums_mfma<<<SUMNB, 512, 0, stream>>>(hbuf, seg, part, E);
  } else {
    const int nz = NGRAPH * 256 * 2 + 64;   // gsum|gsq|gcnt contiguous
    k_zero<<<(nz + 255) / 256, 256, 0, stream>>>(gsum, nz);
    k_edgegemm<false><<<egrid, 512, 0, stream>>>(e, wta, xbc, srcI, dstI,
                                                 batch, hbuf, seg, E, ntiles);
    k_sums_atomic<<<256, 512, 0, stream>>>((const float*)hbuf, seg, gsum, gsq, gcnt, E);
  }
  k_stats<<<NGRAPH, 256, 0, stream>>>(part, NB, gsum, gsq, gcnt, gw, gb, gms, atab, ctab);
  if (fast)
    k_apply<true><<<2048, 256, 0, stream>>>(hbuf, seg, atab, ctab, (float*)d_out, E);
  else
    k_apply<false><<<2048, 256, 0, stream>>>(hbuf, seg, atab, ctab, (float*)d_out, E);
}

// Round 15
// 198.177 us; speedup vs baseline: 1.2170x; 1.1233x over previous
//
#include <hip/hip_runtime.h>
#include <hip/hip_bf16.h>
#include <stdint.h>

// GINE edge layer on MI355X:
//   de = concat([e, x[src], x[dst]]) @ W1 + b1 ; de = silu(de); h = e + de
//   out = GraphNorm(h, seg=batch[src])  (per-graph mean/var, ms-scaled mean)
// Decomposition: concat@W1 = e@W1a + xb[src] + xc[dst], xb/xc per NODE.
// GraphNorm one-pass: var = E[h^2] - m^2*ms*(2-ms); out = A[g,d]*h + C[g,d].
// R2/R3: LDS fp-atomic RMW serializes -> MFMA one-hot segsum.
// R5/R6: e re-read killed; gather chain vectorized (bf16 xbc + b1 fold).
// R7-R13: edgegemm space exhausted (7 variants, 99-153us); R10 persistent+
//   resident-W = 99us floor. Fusion fails (1-blk/CU serial); W-from-L2 fails.
// R14: k_sums 2-blk/CU attempt regressed (+24us: doubled partials + VGPR cap).
// R15: EXACT R10 config restored; k_sums loop re-proven to need only ONE
//   barrier per step (compute(cur) and writeTile(cur^1) touch disjoint LDS;
//   RAW/WAR both covered by the single post-write barrier). Barriers halved.

typedef float   f32x4 __attribute__((ext_vector_type(4)));
typedef short   s16x8 __attribute__((ext_vector_type(8)));
typedef uint32_t u32x4 __attribute__((ext_vector_type(4)));
typedef int     i32x4 __attribute__((ext_vector_type(4)));

#define NGRAPH 64
#define SUMNB  256                      // k_sums grid
#define PSTRIDE (NGRAPH * 256 * 2 + NGRAPH)   // floats per block-partial: sum|sq|cnt

__device__ __forceinline__ void gld16(const void* g, void* l) {
  __builtin_amdgcn_global_load_lds(
      (const __attribute__((address_space(1))) uint32_t*)g,
      (__attribute__((address_space(3))) uint32_t*)l, 16, 0, 0);
}

// native LDS f32 add, no return (tiny per-row counts / fallback only)
__device__ __forceinline__ void ds_addf(float* p, float v) {
  asm volatile("ds_add_f32 %0, %1"
               :: "v"((__attribute__((address_space(3))) float*)p), "v"(v));
}

__device__ __forceinline__ short f2bf(float f) {
  __bf16 b = (__bf16)f;                       // RTNE
  return __builtin_bit_cast(short, b);
}
__device__ __forceinline__ float bf2f(uint32_t u) {
  return __uint_as_float((u & 0xffffu) << 16);
}

// legacy-path permuted d-index (atomic fallback kernel only)
__device__ __forceinline__ int dperm(int d) { return (d >> 3) | ((d & 7) << 5); }

// ---------------------------------------------------------------- zero tables
__global__ __launch_bounds__(256) void k_zero(float* p, int n) {
  int i = blockIdx.x * 256 + threadIdx.x;
  if (i < n) p[i] = 0.f;
}

// ------------------------------------------- W1 f32 [768][256] -> transposed bf16
__global__ __launch_bounds__(256) void k_wconv(const float* __restrict__ W1,
                                               uint16_t* __restrict__ wta,
                                               uint16_t* __restrict__ wtbc) {
  int k = blockIdx.x;            // 0..767
  int n = threadIdx.x;           // 0..255
  uint16_t v = (uint16_t)f2bf(W1[k * 256 + n]);
  if (k < 256)      wta[n * 256 + k] = v;
  else if (k < 512) wtbc[n * 256 + (k - 256)] = v;
  else              wtbc[(n + 256) * 256 + (k - 512)] = v;
}

// ------------------------------------------------- node GEMM: xbc = x @ Wbc (bf16 out)
// xbc[node][0..256) = x@W1b ; xbc[node][256..512) = x@W1c + b1  (b1 folded)
__global__ __launch_bounds__(256, 2) void k_nodegemm(const float* __restrict__ x,
                                                     const uint16_t* __restrict__ wtbc,
                                                     const float* __restrict__ b1,
                                                     uint16_t* __restrict__ xbc, int NV) {
  __shared__ float    xt[32 * 64];
  __shared__ uint16_t wtb[512 * 64];
  const int tid = threadIdx.x, wave = tid >> 6, lane = tid & 63;
  const int m0 = blockIdx.x * 32;
  const int cl = lane & 15, rq = lane >> 4;

  f32x4 acc[2][8];
#pragma unroll
  for (int a = 0; a < 2; ++a)
#pragma unroll
    for (int b = 0; b < 8; ++b) acc[a][b] = (f32x4)0.f;

  for (int kk = 0; kk < 4; ++kk) {
    const int k0 = kk * 64;
#pragma unroll
    for (int ii = 0; ii < 2; ++ii) {
      int i = wave * 2 + ii;
      int row = i * 4 + rq;
      int k8 = cl ^ (row & 15);
      int grow = m0 + row; if (grow > NV - 1) grow = NV - 1;
      gld16((const char*)x + ((size_t)grow * 256 + k0) * 4 + k8 * 16,
            (char*)xt + i * 1024);
    }
#pragma unroll
    for (int ii = 0; ii < 16; ++ii) {
      int i = wave * 16 + ii;
      int n = i * 8 + (lane >> 3);
      int k8 = (lane & 7) ^ (n & 7);
      gld16((const char*)wtbc + ((size_t)n * 256 + k0) * 2 + k8 * 16,
            (char*)wtb + i * 1024);
    }
    __syncthreads();
#pragma unroll
    for (int ks = 0; ks < 2; ++ks) {
      s16x8 a[2], b[8];
#pragma unroll
      for (int mt = 0; mt < 2; ++mt) {
        int row = mt * 16 + cl;
        int sbase = ks * 8 + rq * 2;
        int sw = (row & 15) << 4;
        f32x4 f0 = *(const f32x4*)((const char*)xt + row * 256 + (((sbase    ) << 4) ^ sw));
        f32x4 f1 = *(const f32x4*)((const char*)xt + row * 256 + (((sbase + 1) << 4) ^ sw));
        s16x8 t;
        t[0] = f2bf(f0[0]); t[1] = f2bf(f0[1]); t[2] = f2bf(f0[2]); t[3] = f2bf(f0[3]);
        t[4] = f2bf(f1[0]); t[5] = f2bf(f1[1]); t[6] = f2bf(f1[2]); t[7] = f2bf(f1[3]);
        a[mt] = t;
      }
#pragma unroll
      for (int nt = 0; nt < 8; ++nt) {
        int n = wave * 128 + nt * 16 + cl;
        int byt = n * 128 + ((((ks * 4 + rq)) << 4) ^ ((n & 7) << 4));
        b[nt] = *(const s16x8*)((const char*)wtb + byt);
      }
#pragma unroll
      for (int mt = 0; mt < 2; ++mt)
#pragma unroll
        for (int nt = 0; nt < 8; ++nt)
          acc[mt][nt] = __builtin_amdgcn_mfma_f32_16x16x32_bf16(a[mt], b[nt], acc[mt][nt], 0, 0, 0);
    }
    __syncthreads();
  }
  float b1v[8];
#pragma unroll
  for (int nt = 0; nt < 8; ++nt) {
    int col = wave * 128 + nt * 16 + cl;
    b1v[nt] = (col >= 256) ? b1[col - 256] : 0.f;
  }
#pragma unroll
  for (int mt = 0; mt < 2; ++mt)
#pragma unroll
    for (int q = 0; q < 4; ++q) {
      int row = m0 + mt * 16 + rq * 4 + q;
      if (row < NV) {
#pragma unroll
        for (int nt = 0; nt < 8; ++nt) {
          int col = wave * 128 + nt * 16 + cl;
          xbc[(size_t)row * 512 + col] = (uint16_t)f2bf(acc[mt][nt][q] + b1v[nt]);
        }
      }
    }
}

// ------------------------------------------------- edge GEMM + epilogue (persistent)
// R10 structure (best of 7 variants, 99us): grid<=256 (1 blk/CU), 512 thr =
// 8 waves (2 row-grp x 4 col-grp), grid-stride over 64-row tiles.
// W1a^T RESIDENT in LDS 128 KB: byte = n*512 + ((k8^(n&7))<<4).
// et 32 KB: e-tile (chunk-major) reused as relayout buffer per tile.
template <bool BF16H>
__global__ __launch_bounds__(512, 2) void k_edgegemm(
    const float* __restrict__ e, const uint16_t* __restrict__ wta,
    const uint16_t* __restrict__ xbc,
    const int* __restrict__ srcI, const int* __restrict__ dstI,
    const int* __restrict__ batch, void* __restrict__ hout,
    int* __restrict__ seg, int E, int ntiles) {
  __shared__ alignas(16) uint16_t wl[256 * 256];  // 128 KB resident W1a^T
  __shared__ alignas(16) uint16_t et[64 * 256];   // 32 KB e-tile / relayout
  const int tid = threadIdx.x, wave = tid >> 6, lane = tid & 63;
  const int wr = wave >> 2, wc = wave & 3;
  const int cl = lane & 15, rq = lane >> 4;
  const int rr = tid >> 3;                 // 0..63 (row in tile)
  const int cb = tid & 7;                  // chunk base

  // ---- stage resident W once ----
#pragma unroll
  for (int i = 0; i < 16; ++i) {
    int n = i * 16 + (tid >> 5);
    int k8 = (tid & 31) ^ (n & 7);
    gld16((const char*)wta + ((size_t)n * 256 + k8 * 8) * 2,
          (char*)wl + i * 8192 + tid * 16);
  }

  f32x4 er[8];                             // e prefetch: 4 chunks x 2 f32x4
  auto loadE = [&](int t) {
    int r = t * 64 + rr; int rc = r < E ? r : E - 1;
    const float* ep = e + (size_t)rc * 256;
#pragma unroll
    for (int i = 0; i < 4; ++i) {
      int s = cb + 8 * i;
      er[2 * i]     = *(const f32x4*)(ep + s * 8);
      er[2 * i + 1] = *(const f32x4*)(ep + s * 8 + 4);
    }
  };
  auto writeE = [&]() {
#pragma unroll
    for (int i = 0; i < 4; ++i) {
      int s = cb + 8 * i;
      f32x4 f0 = er[2 * i], f1 = er[2 * i + 1];
      s16x8 t;
      t[0] = f2bf(f0[0]); t[1] = f2bf(f0[1]); t[2] = f2bf(f0[2]); t[3] = f2bf(f0[3]);
      t[4] = f2bf(f1[0]); t[5] = f2bf(f1[1]); t[6] = f2bf(f1[2]); t[7] = f2bf(f1[3]);
      *(s16x8*)((char*)et + s * 1024 + ((rr * 16) ^ ((s & 3) << 4))) = t;
    }
  };

  int t = blockIdx.x;
  const int G = gridDim.x;
  if (t < ntiles) { loadE(t); writeE(); }
  __syncthreads();                          // W staged + e(tile0) visible

  for (; t < ntiles; t += G) {
    const int tn = t + G;
    // idx for current tile
    int r = t * 64 + rr;
    bool valid = r < E;
    int rc = valid ? r : E - 1;
    int sA = srcI[rc], dA = dstI[rc];
    int gseg = batch[sA];
    if (tn < ntiles) loadE(tn);             // prefetch next e (hidden under K-loop)

    // ---- barrier-free K-loop over resident W ----
    f32x4 acc[2][4];
#pragma unroll
    for (int a = 0; a < 2; ++a)
#pragma unroll
      for (int b = 0; b < 4; ++b) acc[a][b] = (f32x4)0.f;
#pragma unroll
    for (int kk = 0; kk < 8; ++kk) {
      s16x8 a[2], b[4];
#pragma unroll
      for (int mt = 0; mt < 2; ++mt) {
        int row = wr * 32 + mt * 16 + cl;
        int c8s = kk * 4 + rq;
        a[mt] = *(const s16x8*)((const char*)et + c8s * 1024 + ((row * 16) ^ (rq << 4)));
      }
#pragma unroll
      for (int nt = 0; nt < 4; ++nt) {
        int n = wc * 64 + nt * 16 + cl;
        int kc = kk * 4 + rq;
        b[nt] = *(const s16x8*)((const char*)wl + n * 512 + ((kc ^ (n & 7)) << 4));
      }
#pragma unroll
      for (int mt = 0; mt < 2; ++mt)
#pragma unroll
        for (int nt = 0; nt < 4; ++nt)
          acc[mt][nt] = __builtin_amdgcn_mfma_f32_16x16x32_bf16(a[mt], b[nt], acc[mt][nt], 0, 0, 0);
    }

    // ---- gathers for current tile (L3; consumed after 2 barriers) ----
    u32x4 gb[4], gc[4];
#pragma unroll
    for (int i = 0; i < 4; ++i) {
      int c8 = cb + 8 * i;
      gb[i] = *(const u32x4*)(xbc + (size_t)sA * 512 + c8 * 8);
      gc[i] = *(const u32x4*)(xbc + (size_t)dA * 512 + 256 + c8 * 8);
    }
    // ---- e residual out of et before relayout clobbers it ----
    s16x8 ev[4];
#pragma unroll
    for (int i = 0; i < 4; ++i) {
      int c8 = cb + 8 * i;
      ev[i] = *(const s16x8*)((const char*)et + c8 * 1024 + ((rr * 16) ^ ((c8 & 3) << 4)));
    }
    __syncthreads();

    // ---- relayout acc -> et (bf16, chunk-major) ----
#pragma unroll
    for (int mt = 0; mt < 2; ++mt)
#pragma unroll
      for (int nt = 0; nt < 4; ++nt) {
        int col = wc * 64 + nt * 16 + cl;
        int c8 = col >> 3;
        char* base = (char*)et + c8 * 1024 + (col & 7) * 2;
#pragma unroll
        for (int q = 0; q < 4; ++q) {
          int row = wr * 32 + mt * 16 + rq * 4 + q;
          *(uint16_t*)(base + ((row * 16) ^ ((c8 & 3) << 4))) =
              (uint16_t)f2bf(acc[mt][nt][q]);
        }
      }
    __syncthreads();

    // ---- combine + store ----
    if (cb == 0 && valid) seg[r] = gseg;
#pragma unroll
    for (int i = 0; i < 4; ++i) {
      int c8 = cb + 8 * i;
      int sw = (c8 & 3) << 4;
      s16x8 av = *(const s16x8*)((const char*)et + c8 * 1024 + ((rr * 16) ^ sw));
      s16x8 ho;
      f32x4 f0, f1;
#pragma unroll
      for (int j = 0; j < 8; ++j) {
        uint32_t xbw = ((const uint32_t*)&gb[i])[j >> 1];
        uint32_t xcw = ((const uint32_t*)&gc[i])[j >> 1];
        float xbf = bf2f((j & 1) ? (xbw >> 16) : xbw);
        float xcf = bf2f((j & 1) ? (xcw >> 16) : xcw);
        float de = bf2f((uint16_t)av[j]) + xbf + xcf;      // b1 folded in xc
        float sig = 1.f / (1.f + __expf(-de));
        float h = bf2f((uint16_t)ev[i][j]) + de * sig;
        if (BF16H) ho[j] = f2bf(h);
        else { if (j < 4) f0[j] = h; else f1[j - 4] = h; }
      }
      if (valid) {
        if (BF16H) {
          *(s16x8*)((uint16_t*)hout + (size_t)r * 256 + c8 * 8) = ho;
        } else {
          float* hp_ = (float*)hout + (size_t)r * 256 + c8 * 8;
          *(f32x4*)hp_ = f0; *(f32x4*)(hp_ + 4) = f1;
        }
      }
    }
    __syncthreads();                        // et reads done before next e write

    if (tn < ntiles) writeE();              // stage e for next tile
    __syncthreads();
  }
}

// ------------------------------------------------- segment sums via one-hot MFMA
// sum[g,d] = P[g,r] @ H[r,d], sq[g,d] = P @ (H.^2); P one-hot from seg.
// R15: single barrier per 32-row step (compute(cur) and writeTile(cur^1) touch
// DISJOINT buffers; RAW into next compute and WAR vs previous compute are both
// covered by the one post-write barrier).
__global__ __launch_bounds__(512, 1) void k_sums_mfma(
    const void* __restrict__ hsrc, const int* __restrict__ seg,
    float* __restrict__ part, int E) {
  __shared__ alignas(16) uint16_t hb[2][32 * 256];   // byte = d*64 + ((r*2)^((d&3)<<4))
  __shared__ alignas(16) int      sg[2][32];
  __shared__ float lcnt[NGRAPH];
  const int tid = threadIdx.x;
  const int lane = tid & 63, wv = tid >> 6;
  const int cl = lane & 15, rq = lane >> 4;
  const int d0 = wv * 32;
  const int sr = tid & 15;          // row-pair: rows sr*2, sr*2+1
  const int d8 = tid >> 4;          // 0..31 -> d-range [d8*8, d8*8+8)

  if (tid < NGRAPH) lcnt[tid] = 0.f;

  f32x4 accS[4][2], accQ[4][2];
#pragma unroll
  for (int gt = 0; gt < 4; ++gt)
#pragma unroll
    for (int dt = 0; dt < 2; ++dt) { accS[gt][dt] = (f32x4)0.f; accQ[gt][dt] = (f32x4)0.f; }

  uint32_t q0[4], q1[4];            // packed bf16 pairs, rows sr*2 / sr*2+1
  int sgv = 0;

  auto loadTile = [&](int rt) {
    const uint16_t* hp = (const uint16_t*)hsrc;
    int r2 = rt + sr * 2;
    u32x4 a = (r2 < E)     ? *(const u32x4*)(hp + (size_t)r2 * 256 + d8 * 8)       : (u32x4)0u;
    u32x4 b = (r2 + 1 < E) ? *(const u32x4*)(hp + (size_t)(r2 + 1) * 256 + d8 * 8) : (u32x4)0u;
#pragma unroll
    for (int i = 0; i < 4; ++i) { q0[i] = a[i]; q1[i] = b[i]; }
    if (tid < 32) sgv = (rt + tid < E) ? seg[rt + tid] : 0;
  };
  auto writeTile = [&](int buf) {
#pragma unroll
    for (int i = 0; i < 4; ++i) {
      int da = d8 * 8 + 2 * i, db = da + 1;
      uint32_t lo = q0[i], hi = q1[i];
      uint32_t w0 = (lo & 0xffffu) | (hi << 16);
      uint32_t w1 = (lo >> 16) | (hi & 0xffff0000u);
      *(uint32_t*)((char*)hb[buf] + da * 64 + ((sr * 4) ^ ((da & 3) << 4))) = w0;
      *(uint32_t*)((char*)hb[buf] + db * 64 + ((sr * 4) ^ ((db & 3) << 4))) = w1;
    }
    if (tid < 32) sg[buf][tid] = sgv;
  };
  auto compute = [&](int buf, int rt) {
    i32x4 s01 = *(const i32x4*)&sg[buf][rq * 8];
    i32x4 s23 = *(const i32x4*)&sg[buf][rq * 8 + 4];
    int segv[8] = {s01[0], s01[1], s01[2], s01[3], s23[0], s23[1], s23[2], s23[3]};
    s16x8 af[4];
#pragma unroll
    for (int gt = 0; gt < 4; ++gt) {
      int gcol = gt * 16 + cl;
      u32x4 aw;
#pragma unroll
      for (int jp = 0; jp < 4; ++jp)
        aw[jp] = (segv[2 * jp]     == gcol ? 0x3F80u     : 0u)
               | (segv[2 * jp + 1] == gcol ? 0x3F800000u : 0u);
      af[gt] = __builtin_bit_cast(s16x8, aw);
    }
#pragma unroll
    for (int dt = 0; dt < 2; ++dt) {
      int d = d0 + dt * 16 + cl;
      s16x8 bf = *(const s16x8*)((const char*)hb[buf] + d * 64 + ((rq * 16) ^ ((d & 3) << 4)));
      s16x8 qf;
#pragma unroll
      for (int i = 0; i < 8; ++i) {
        float f = __uint_as_float(((uint32_t)(uint16_t)bf[i]) << 16);
        qf[i] = f2bf(f * f);
      }
#pragma unroll
      for (int gt = 0; gt < 4; ++gt) {
        accS[gt][dt] = __builtin_amdgcn_mfma_f32_16x16x32_bf16(af[gt], bf, accS[gt][dt], 0, 0, 0);
        accQ[gt][dt] = __builtin_amdgcn_mfma_f32_16x16x32_bf16(af[gt], qf, accQ[gt][dt], 0, 0, 0);
      }
    }
    if (tid < 32 && rt + tid < E) ds_addf(&lcnt[sg[buf][tid]], 1.f);
  };

  const int STEP = SUMNB * 32;      // 8192 rows per sweep
  int r0 = blockIdx.x * 32;
  if (r0 < E) { loadTile(r0); writeTile(0); }
  __syncthreads();
  int cur = 0;
  while (r0 < E) {
    int rn = r0 + STEP;
    bool more = rn < E;
    if (more) loadTile(rn);         // issue-early: HBM latency hides under MFMA
    compute(cur, r0);               // reads hb[cur]/sg[cur]
    if (more) writeTile(cur ^ 1);   // writes hb[cur^1]/sg[cur^1] (disjoint)
    __syncthreads();                // single barrier: RAW for next compute,
    cur ^= 1;                       // WAR vs previous compute both covered
    r0 = rn;
  }
  asm volatile("s_waitcnt lgkmcnt(0)" ::: "memory");   // drain asm ds_add (counts)
  __syncthreads();

  float* pb = part + (size_t)blockIdx.x * PSTRIDE;
#pragma unroll
  for (int gt = 0; gt < 4; ++gt)
#pragma unroll
    for (int dt = 0; dt < 2; ++dt)
#pragma unroll
      for (int qq = 0; qq < 4; ++qq) {
        int g = gt * 16 + rq * 4 + qq;          // C-frag: row=(lane>>4)*4+reg
        int d = d0 + dt * 16 + cl;              //         col=lane&15
        pb[g * 256 + d] = accS[gt][dt][qq];
        pb[NGRAPH * 256 + g * 256 + d] = accQ[gt][dt][qq];
      }
  if (tid < NGRAPH) pb[NGRAPH * 256 * 2 + tid] = lcnt[tid];
}

// ------------------------------------------------- legacy atomic k_sums (fallback)
__global__ __launch_bounds__(512, 1) void k_sums_atomic(const float* __restrict__ h,
                                                        const int* __restrict__ seg,
                                                        float* __restrict__ gsum,
                                                        float* __restrict__ gsq,
                                                        float* __restrict__ gcnt, int E) {
  __shared__ float ls[NGRAPH * 256];      // d-permuted layout
  __shared__ float lq[NGRAPH * 256];
  __shared__ float lc[NGRAPH];
  const int t = threadIdx.x;
  for (int i = t; i < NGRAPH * 256; i += 512) { ls[i] = 0.f; lq[i] = 0.f; }
  if (t < NGRAPH) lc[t] = 0.f;
  __syncthreads();
  const int ro = t >> 5, c = t & 31;
  const int step = gridDim.x * 16;
  for (int r0 = blockIdx.x * 16; r0 < E; r0 += step) {
    int r = r0 + ro;
    if (r < E) {
      int g = seg[r];
      const float* hp = h + (size_t)r * 256 + c * 8;
      if (c == 0) ds_addf(&lc[g], 1.f);
      float* bs = ls + g * 256;
      float* bq = lq + g * 256;
#pragma unroll
      for (int j = 0; j < 8; ++j) {
        int dp = c | (j << 5);
        float v = hp[j];
        ds_addf(&bs[dp], v);
        ds_addf(&bq[dp], v * v);
      }
    }
  }
  asm volatile("s_waitcnt lgkmcnt(0)" ::: "memory");
  __syncthreads();
  for (int i = t; i < NGRAPH * 256; i += 512) {
    unsafeAtomicAdd(&gsum[i], ls[i]);
    unsafeAtomicAdd(&gsq[i], lq[i]);
  }
  if (t < NGRAPH) unsafeAtomicAdd(&gcnt[t], lc[t]);
}

// ------------------------------------------------- per-(g,d) affine tables
// NB>0: reduce NB block-partials (natural layout); NB==0: legacy dperm'd tables
__global__ __launch_bounds__(256) void k_stats(const float* __restrict__ part, int NB,
                                               const float* __restrict__ gsum,
                                               const float* __restrict__ gsq,
                                               const float* __restrict__ gcnt,
                                               const float* __restrict__ w,
                                               const float* __restrict__ b,
                                               const float* __restrict__ ms,
                                               float* __restrict__ atab,
                                               float* __restrict__ ctab) {
  int g = blockIdx.x, d = threadIdx.x;
  float s = 0.f, q = 0.f, cn = 0.f;
  if (NB > 0) {
    const float* ps = part + g * 256 + d;
    const float* pq = part + NGRAPH * 256 + g * 256 + d;
    const float* pc = part + NGRAPH * 256 * 2 + g;
#pragma unroll 4
    for (int bb = 0; bb < NB; ++bb) {
      size_t o = (size_t)bb * PSTRIDE;
      s  += ps[o];
      q  += pq[o];
      cn += pc[o];
    }
  } else {
    int dp = dperm(d);
    s = gsum[g * 256 + dp]; q = gsq[g * 256 + dp]; cn = gcnt[g];
  }
  float cnt = fmaxf(cn, 1.f);
  float m   = s / cnt;
  float msq = q / cnt;
  float sc  = ms[d];
  float var = msq - m * m * sc * (2.f - sc);
  float rstd = rsqrtf(fmaxf(var, 0.f) + 1e-5f);
  float A = w[d] * rstd;
  atab[g * 256 + d] = A;
  ctab[g * 256 + d] = b[d] - A * sc * m;
}

// ------------------------------------------------- apply: out = A[g]*h + C[g]
template <bool BF16H>
__global__ __launch_bounds__(256) void k_apply(const void* __restrict__ h,
                                               const int* __restrict__ seg,
                                               const float* __restrict__ atab,
                                               const float* __restrict__ ctab,
                                               float* __restrict__ out, int E) {
  const long long total = (long long)E * 32;
  for (long long i = (long long)blockIdx.x * 256 + threadIdx.x; i < total;
       i += (long long)gridDim.x * 256) {
    int row = (int)(i >> 5);
    int c8 = ((int)i & 31) * 8;
    int g = seg[row];
    const f32x4* Ap = (const f32x4*)(atab + g * 256 + c8);
    const f32x4* Cp = (const f32x4*)(ctab + g * 256 + c8);
    f32x4 A0 = Ap[0], A1 = Ap[1], C0 = Cp[0], C1 = Cp[1];
    f32x4 h0, h1;
    if (BF16H) {
      u32x4 p = *(const u32x4*)((const uint16_t*)h + (size_t)row * 256 + c8);
      h0[0] = bf2f(p[0]); h0[1] = bf2f(p[0] >> 16);
      h0[2] = bf2f(p[1]); h0[3] = bf2f(p[1] >> 16);
      h1[0] = bf2f(p[2]); h1[1] = bf2f(p[2] >> 16);
      h1[2] = bf2f(p[3]); h1[3] = bf2f(p[3] >> 16);
    } else {
      const f32x4* hp = (const f32x4*)((const float*)h + (size_t)row * 256 + c8);
      h0 = hp[0]; h1 = hp[1];
    }
    f32x4 o0 = A0 * h0 + C0, o1 = A1 * h1 + C1;
    f32x4* op = (f32x4*)(out + (size_t)row * 256 + c8);
    op[0] = o0; op[1] = o1;
  }
}

// ----------------------------------------------------------------- launch
extern "C" void kernel_launch(void* const* d_in, const int* in_sizes, int n_in,
                              void* d_out, int out_size, void* d_ws, size_t ws_size,
                              hipStream_t stream) {
  const float* x     = (const float*)d_in[0];
  const float* e     = (const float*)d_in[1];
  const int*   batch = (const int*)d_in[2];
  const int*   eidx  = (const int*)d_in[3];
  const float* W1    = (const float*)d_in[4];
  const float* b1    = (const float*)d_in[5];
  const float* gw    = (const float*)d_in[6];
  const float* gb    = (const float*)d_in[7];
  const float* gms   = (const float*)d_in[8];
  const int NV = in_sizes[0] / 256;
  const int E  = in_sizes[1] / 256;
  const int* srcI = eidx;
  const int* dstI = eidx + E;

  char* ws = (char*)d_ws;
  size_t off = 0;
  auto alloc = [&](size_t bytes) {
    size_t o = off;
    off += (bytes + 255) & ~(size_t)255;
    return o;
  };
  size_t o_wta  = alloc(256 * 256 * 2);
  size_t o_wtbc = alloc(512 * 256 * 2);
  size_t o_gsum = alloc(NGRAPH * 256 * 4);
  size_t o_gsq  = alloc(NGRAPH * 256 * 4);
  size_t o_gcnt = alloc(256);
  size_t o_atab = alloc(NGRAPH * 256 * 4);
  size_t o_ctab = alloc(NGRAPH * 256 * 4);
  size_t o_seg  = alloc((size_t)E * 4);
  size_t o_xbc  = alloc((size_t)NV * 512 * 2);     // bf16
  size_t o_h    = alloc((size_t)E * 256 * 2);
  const bool fast = ws_size >= off;   // h (bf16) fits in ws? else stage f32 in d_out

  uint16_t* wta  = (uint16_t*)(ws + o_wta);
  uint16_t* wtbc = (uint16_t*)(ws + o_wtbc);
  float* gsum = (float*)(ws + o_gsum);
  float* gsq  = (float*)(ws + o_gsq);
  float* gcnt = (float*)(ws + o_gcnt);
  float* atab = (float*)(ws + o_atab);
  float* ctab = (float*)(ws + o_ctab);
  int*   seg  = (int*)(ws + o_seg);
  uint16_t* xbc = (uint16_t*)(ws + o_xbc);
  void*  hbuf = fast ? (void*)(ws + o_h) : d_out;
  // fast path: block-partials at the START of d_out (33.6 MB << 164 MB);
  // consumed by k_stats, then fully overwritten by k_apply. Deterministic.
  float* part = fast ? (float*)d_out : nullptr;
  const int NB = fast ? SUMNB : 0;

  const int ntiles = (E + 63) / 64;
  const int egrid = ntiles < 256 ? ntiles : 256;

  k_wconv<<<768, 256, 0, stream>>>(W1, wta, wtbc);
  k_nodegemm<<<(NV + 31) / 32, 256, 0, stream>>>(x, wtbc, b1, xbc, NV);
  if (fast) {
    k_edgegemm<true><<<egrid, 512, 0, stream>>>(e, wta, xbc, srcI, dstI,
                                                batch, hbuf, seg, E, ntiles);
    k_sums_mfma<<<SUMNB, 512, 0, stream>>>(hbuf, seg, part, E);
  } else {
    const int nz = NGRAPH * 256 * 2 + 64;   // gsum|gsq|gcnt contiguous
    k_zero<<<(nz + 255) / 256, 256, 0, stream>>>(gsum, nz);
    k_edgegemm<false><<<egrid, 512, 0, stream>>>(e, wta, xbc, srcI, dstI,
                                                 batch, hbuf, seg, E, ntiles);
    k_sums_atomic<<<256, 512, 0, stream>>>((const float*)hbuf, seg, gsum, gsq, gcnt, E);
  }
  k_stats<<<NGRAPH, 256, 0, stream>>>(part, NB, gsum, gsq, gcnt, gw, gb, gms, atab, ctab);
  if (fast)
    k_apply<true><<<2048, 256, 0, stream>>>(hbuf, seg, atab, ctab, (float*)d_out, E);
  else
    k_apply<false><<<2048, 256, 0, stream>>>(hbuf, seg, atab, ctab, (float*)d_out, E);
}